// Round 15
// baseline (1373.066 us; speedup 1.0000x reference)
//
#include <hip/hip_runtime.h>
#include <hip/hip_bf16.h>

typedef __bf16 bf16_t;
typedef __bf16 bf16x4 __attribute__((ext_vector_type(4)));
typedef __bf16 bf16x8 __attribute__((ext_vector_type(8)));
typedef float f32x4 __attribute__((ext_vector_type(4)));

#define BB 2
#define SS 4096
#define DD 1024
#define VV 32000
#define HH 8
#define CC 256
#define NC 16

#define GLD_LDS16(gp, lp) __builtin_amdgcn_global_load_lds( \
    (const __attribute__((address_space(1))) void*)(gp),    \
    (__attribute__((address_space(3))) void*)(lp), 16, 0, 0)

// ---------------- ctx: emb gather + 4-tap causal sum (bf16 only) ----------------
__global__ __launch_bounds__(256) void ctx_kernel(
    const int* __restrict__ x, const float* __restrict__ emb,
    bf16_t* __restrict__ ctxb)
{
  const int row = blockIdx.x;            // b*SS + s
  const int b = row >> 12, s = row & (SS - 1);
  const int t = threadIdx.x;             // d = t*4
  float4 a = make_float4(0.f, 0.f, 0.f, 0.f);
  #pragma unroll
  for (int o = 0; o < 4; ++o) {
    if (s - o >= 0) {
      const int idx = x[b * SS + s - o];
      const float4 e = *(const float4*)(emb + (size_t)idx * DD + t * 4);
      a.x += e.x; a.y += e.y; a.z += e.z; a.w += e.w;
    }
  }
  bf16x4 bv;
  bv[0] = (__bf16)a.x; bv[1] = (__bf16)a.y; bv[2] = (__bf16)a.z; bv[3] = (__bf16)a.w;
  *(bf16x4*)(ctxb + (size_t)row * DD + t * 4) = bv;
}

// ------- transpose + f32->bf16, 128x64 tile: dst[c][r]=src[r][c], 256B dst writes -------
__global__ __launch_bounds__(256) void transpose_cvt(
    const float* __restrict__ src, bf16_t* __restrict__ dst,
    int srcRows, int srcCols)
{
  __shared__ __align__(16) float tile[128][65];
  const int c0 = blockIdx.x * 64, r0 = blockIdx.y * 128;
  const int t = threadIdx.x;
  #pragma unroll
  for (int p = 0; p < 8; ++p) {
    const int r = p * 16 + (t >> 4);
    const int c = (t & 15) * 4;
    *(float4*)&tile[r][c] = *(const float4*)(src + (size_t)(r0 + r) * srcCols + c0 + c);
  }
  __syncthreads();
  #pragma unroll
  for (int p = 0; p < 4; ++p) {
    const int j = p * 16 + (t >> 4);     // dst row (src col)
    const int i0 = (t & 15) * 8;         // src row offset
    bf16x8 v;
    #pragma unroll
    for (int e = 0; e < 8; ++e) v[e] = (__bf16)tile[i0 + e][j];
    *(bf16x8*)(dst + (size_t)(c0 + j) * srcRows + r0 + i0) = v;
  }
}

// ========== m97-structure 128x128 GEMM, BK=64, 4 waves ==========
// R15: single change vs R14 -- __launch_bounds__(256,5): LDS pool 160KB /
// 32KB = 5 blocks/CU fit exactly (was capped at 4). +25% co-resident MFMA
// work to hide each block's vmcnt(0)+barrier drain (m114 implicit overlap
// is this family's pipelining mechanism; R12/R13 proved explicit overlap
// destroys panel L2 reuse).
// EPI: 1 = +bias[col] -> f32 C (logits, nontemporal); 2 = +bf16 residual ->
// bf16 Cb (Wo); 3 = QKV epilogue (phi q/k -> qb/kb, v -> transposed vtb).
template<int EPI>
__global__ __launch_bounds__(256, 5) void gemm128_kernel(
    const bf16_t* __restrict__ A, const bf16_t* __restrict__ BT,
    float* __restrict__ C, bf16_t* __restrict__ Cb,
    const float* __restrict__ extraF, const bf16_t* __restrict__ extraB,
    bf16_t* __restrict__ qb, bf16_t* __restrict__ kbx, bf16_t* __restrict__ vtb,
    int N, int K)
{
  __shared__ __align__(16) bf16_t As[128 * 64];
  __shared__ __align__(16) bf16_t Bs[128 * 64];
  const int bid = blockIdx.x;
  const int i = bid >> 3, xcd = bid & 7;
  const int by = xcd * 8 + (i & 7);          // GY = M/128 = 64 always (M=8192)
  const int bx = i >> 3;
  const int n0 = bx * 128, m0 = by * 128;
  const int t = threadIdx.x;
  const int w = t >> 6, lane = t & 63;
  const int wm = (w >> 1) * 64, wn = (w & 1) * 64;
  const int lr = lane & 15, lq = lane >> 4;
  f32x4 acc[4][4] = {};

  for (int k0 = 0; k0 < K; k0 += 64) {
    #pragma unroll
    for (int j = 0; j < 4; ++j) {
      const int idx = j * 256 + t;
      const int r = idx >> 3;
      const int sc = ((idx & 7) ^ (r & 7)) * 8;      // pre-swizzled src col
      GLD_LDS16(A  + (size_t)(m0 + r) * K + k0 + sc, As + (size_t)idx * 8);
      GLD_LDS16(BT + (size_t)(n0 + r) * K + k0 + sc, Bs + (size_t)idx * 8);
    }
    asm volatile("s_waitcnt vmcnt(0)" ::: "memory");
    __syncthreads();
    bf16x8 af[4][2], bfr[4][2];
    #pragma unroll
    for (int ii = 0; ii < 4; ++ii) {
      const int ra = wm + ii * 16 + lr;
      const int rb = wn + ii * 16 + lr;
      #pragma unroll
      for (int ks = 0; ks < 2; ++ks) {
        const int col = ((ks * 4 + lq) ^ (lr & 7)) * 8;   // swizzled read col
        af[ii][ks]  = *(const bf16x8*)(As + ra * 64 + col);
        bfr[ii][ks] = *(const bf16x8*)(Bs + rb * 64 + col);
      }
    }
    #pragma unroll
    for (int mi = 0; mi < 4; ++mi)
      #pragma unroll
      for (int ni = 0; ni < 4; ++ni) {
        acc[mi][ni] = __builtin_amdgcn_mfma_f32_16x16x32_bf16(af[mi][0], bfr[ni][0], acc[mi][ni], 0, 0, 0);
        acc[mi][ni] = __builtin_amdgcn_mfma_f32_16x16x32_bf16(af[mi][1], bfr[ni][1], acc[mi][ni], 0, 0, 0);
      }
    __syncthreads();
  }

  // C/D layout: col=lane&15, row=(lane>>4)*4+reg  [m89-verified]
  if (EPI == 3) {
    #pragma unroll
    for (int mi = 0; mi < 4; ++mi) {
      const int row0 = m0 + wm + mi * 16 + lq * 4;
      #pragma unroll
      for (int ni = 0; ni < 4; ++ni) {
        const int col = n0 + wn + ni * 16 + lr;
        if (col < 256) {                       // q | k : phi -> bf16 (block-uniform)
          #pragma unroll
          for (int r = 0; r < 4; ++r) {
            float v = acc[mi][ni][r];
            v = v > 0.f ? v + 1.f : __expf(v);
            if (col < 128) qb [(size_t)(row0 + r) * 128 + col      ] = (__bf16)v;
            else           kbx[(size_t)(row0 + r) * 128 + col - 128] = (__bf16)v;
          }
        } else {                               // v -> transposed bf16
          const int vcol = col - 256;
          const int hh = vcol >> 7, dv = vcol & 127;
          const int bb = row0 >> 12, s0 = row0 & (SS - 1);
          bf16x4 pv;
          #pragma unroll
          for (int r = 0; r < 4; ++r) pv[r] = (__bf16)acc[mi][ni][r];
          *(bf16x4*)(vtb + ((size_t)((bb * HH + hh) * 128 + dv)) * SS + s0) = pv;
        }
      }
    }
    return;
  }
  #pragma unroll
  for (int mi = 0; mi < 4; ++mi) {
    #pragma unroll
    for (int r = 0; r < 4; ++r) {
      const int row = m0 + wm + mi * 16 + lq * 4 + r;
      #pragma unroll
      for (int ni = 0; ni < 4; ++ni) {
        const int col = n0 + wn + ni * 16 + lr;
        float v = acc[mi][ni][r];
        if (EPI == 1) {
          v += extraF[col];
          __builtin_nontemporal_store(v, &C[(size_t)row * N + col]);
        }
        if (EPI == 2) {
          v += (float)extraB[(size_t)row * N + col];
          Cb[(size_t)row * N + col] = (__bf16)v;
        }
      }
    }
  }
}

// ---------------- per-chunk G = K^T V (MFMA) and ksum ----------------
__global__ __launch_bounds__(64) void gstate_kernel(
    const bf16_t* __restrict__ kb, const bf16_t* __restrict__ vT,
    float* __restrict__ G, float* __restrict__ KS)
{
  const int bid = blockIdx.x;                  // b*128 + c*8 + h
  const int h = bid & 7, c = (bid >> 3) & 15, b = bid >> 7;
  const int lane = threadIdx.x;
  const int lr = lane & 15, lq = lane >> 4;
  __shared__ __align__(16) bf16_t ktl[16][264]; // k transposed: [i][s]
  for (int ss = 0; ss < 4; ++ss) {
    const int s = ss * 64 + lane;
    const bf16_t* src = kb + (size_t)(b * SS + c * CC + s) * 128 + h * 16;
    const bf16x8 v0 = *(const bf16x8*)src;
    const bf16x8 v1 = *(const bf16x8*)(src + 8);
    #pragma unroll
    for (int ii = 0; ii < 8; ++ii) { ktl[ii][s] = v0[ii]; ktl[8 + ii][s] = v1[ii]; }
  }
  __syncthreads();
  if (lane < 16) {
    float ks = 0.f;
    for (int s = 0; s < 256; ++s) ks += (float)ktl[lane][s];
    KS[((size_t)((b * NC + c) * HH + h)) * 16 + lane] = ks;
  }
  bf16x8 af[8];
  #pragma unroll
  for (int sk = 0; sk < 8; ++sk)
    af[sk] = *(const bf16x8*)&ktl[lr][sk * 32 + lq * 8];
  float* gout = G + ((size_t)((b * NC + c) * HH + h)) * 2048;
  #pragma unroll
  for (int nf = 0; nf < 8; ++nf) {
    f32x4 acc = {0.f, 0.f, 0.f, 0.f};
    #pragma unroll
    for (int sk = 0; sk < 8; ++sk) {
      const bf16x8 vb = *(const bf16x8*)(vT +
          ((size_t)((b * HH + h) * 128 + nf * 16 + lr)) * SS + c * CC + sk * 32 + lq * 8);
      acc = __builtin_amdgcn_mfma_f32_16x16x32_bf16(af[sk], vb, acc, 0, 0, 0);
    }
    #pragma unroll
    for (int r = 0; r < 4; ++r)
      gout[(size_t)(lq * 4 + r) * 128 + nf * 16 + lr] = acc[r];
  }
}

// ---------------- MFMA attention: intra(masked) + bypass + state ----------------
__global__ __launch_bounds__(512, 2) void attn_kernel(
    const bf16_t* __restrict__ qb, const bf16_t* __restrict__ kb,
    const bf16_t* __restrict__ vT, const float* __restrict__ Gb,
    const float* __restrict__ KS, bf16_t* __restrict__ outp)
{
  const int bid = blockIdx.x;                  // b*128 + c*8 + h
  const int h = bid & 7, c = (bid >> 3) & 15, b = bid >> 7;
  const int t = threadIdx.x;
  const int w = t >> 6, lane = t & 63;
  const int lr = lane & 15, lq = lane >> 4;
  const int rowbase = b * SS + c * CC;

  __shared__ __align__(16) bf16_t q_lds[256][24];
  __shared__ __align__(16) bf16_t k_lds[512][24];
  __shared__ __align__(16) bf16_t vt_lds[128][72];
  __shared__ __align__(16) bf16_t p_lds[8][32][72];
  __shared__ float s_f32[16][128];
  __shared__ float z_lds[16];
  __shared__ float dstate[256];

  if (t < 256) {                               // stage q rows (bf16, 32B each)
    const bf16_t* src = qb + (size_t)(rowbase + t) * 128 + h * 16;
    *(uint4*)&q_lds[t][0] = *(const uint4*)src;
    *(uint4*)&q_lds[t][8] = *(const uint4*)(src + 8);
  }
  {                                            // stage k rows: prev | cur
    if (t < 256 && c == 0) {
      const uint4 z = {0u, 0u, 0u, 0u};
      *(uint4*)&k_lds[t][0] = z; *(uint4*)&k_lds[t][8] = z;
    } else {
      const int sg = (t < 256) ? (c - 1) * CC + t : c * CC + (t - 256);
      const bf16_t* src = kb + (size_t)(b * SS + sg) * 128 + h * 16;
      *(uint4*)&k_lds[t][0] = *(const uint4*)src;
      *(uint4*)&k_lds[t][8] = *(const uint4*)(src + 8);
    }
  }
  if (t < 16) {                                // z[i] = sum_{j<=c-2} ksum_j[i]
    float z = 0.f;
    for (int j = 0; j + 2 <= c; ++j) z += KS[((size_t)((b * NC + j) * HH + h)) * 16 + t];
    z_lds[t] = z;
  }
  if (c >= 2) {                                // S = sum_{j<=c-2} G_j
    for (int idx = t; idx < 2048; idx += 512) {
      float sv = 0.f;
      for (int j = 0; j + 2 <= c; ++j)
        sv += Gb[((size_t)((b * NC + j) * HH + h)) * 2048 + idx];
      ((float*)s_f32)[idx] = sv;
    }
  }
  __syncthreads();
  if (t < 256) {                               // dstate[row] = q[row].z
    float d = 0.f;
    #pragma unroll
    for (int ii = 0; ii < 16; ++ii) d += (float)q_lds[t][ii] * z_lds[ii];
    dstate[t] = d;
  }

  const int wrow = w * 32;
  bf16x8 qf[2];
  #pragma unroll
  for (int mi = 0; mi < 2; ++mi) {
    bf16x8 v = {};
    if (lq < 2) v = *(const bf16x8*)&q_lds[wrow + mi * 16 + lr][lq * 8];
    qf[mi] = v;
  }
  f32x4 acc[2][8] = {};
  float den_l[2][4] = {};
  const int nc0 = (c == 0) ? 4 : 0;

  for (int nc = nc0; nc < 8; ++nc) {
    __syncthreads();                           // vt_lds reuse safe
    {                                          // stage V^T chunk [128 dv][64 keys]
      const int dv = t >> 2, kk = (t & 3) * 16;
      const int key0 = nc * 64;
      const int sg = (key0 < 256) ? (c - 1) * CC + key0 : c * CC + key0 - 256;
      const bf16_t* src = vT + ((size_t)((b * HH + h) * 128 + dv)) * SS + sg + kk;
      *(uint4*)&vt_lds[dv][kk]     = *(const uint4*)src;
      *(uint4*)&vt_lds[dv][kk + 8] = *(const uint4*)(src + 8);
    }
    __syncthreads();
    f32x4 attf[2][4];
    #pragma unroll
    for (int nf = 0; nf < 4; ++nf) {
      bf16x8 kv = {};
      if (lq < 2) kv = *(const bf16x8*)&k_lds[nc * 64 + nf * 16 + lr][lq * 8];
      #pragma unroll
      for (int mi = 0; mi < 2; ++mi) {
        const f32x4 zero = {0.f, 0.f, 0.f, 0.f};
        attf[mi][nf] = __builtin_amdgcn_mfma_f32_16x16x32_bf16(qf[mi], kv, zero, 0, 0, 0);
      }
    }
    #pragma unroll
    for (int mi = 0; mi < 2; ++mi)
      #pragma unroll
      for (int nf = 0; nf < 4; ++nf)
        #pragma unroll
        for (int r = 0; r < 4; ++r) {
          const int row_l = wrow + mi * 16 + lq * 4 + r;
          const int key_l = nc * 64 + nf * 16 + lr;
          float a = attf[mi][nf][r];
          if (key_l >= 256 && key_l - 256 > row_l) a = 0.f;
          den_l[mi][r] += a;
          p_lds[w][mi * 16 + lq * 4 + r][nf * 16 + lr] = (__bf16)a;
        }
    #pragma unroll
    for (int ks = 0; ks < 2; ++ks) {
      bf16x8 pa[2];
      #pragma unroll
      for (int mi = 0; mi < 2; ++mi)
        pa[mi] = *(const bf16x8*)&p_lds[w][mi * 16 + lr][ks * 32 + lq * 8];
      #pragma unroll
      for (int nf = 0; nf < 8; ++nf) {
        const bf16x8 vb = *(const bf16x8*)&vt_lds[nf * 16 + lr][ks * 32 + lq * 8];
        #pragma unroll
        for (int mi = 0; mi < 2; ++mi)
          acc[mi][nf] = __builtin_amdgcn_mfma_f32_16x16x32_bf16(pa[mi], vb, acc[mi][nf], 0, 0, 0);
      }
    }
  }

  if (c >= 2) {                                // state numerator: acc += q.S
    #pragma unroll
    for (int mi = 0; mi < 2; ++mi)
      for (int r = 0; r < 4; ++r) {
        const int row_l = wrow + mi * 16 + lq * 4 + r;
        float qrow[16];
        #pragma unroll
        for (int ii = 0; ii < 16; ++ii) qrow[ii] = (float)q_lds[row_l][ii];
        #pragma unroll
        for (int nf = 0; nf < 8; ++nf) {
          float sacc = 0.f;
          #pragma unroll
          for (int ii = 0; ii < 16; ++ii) sacc += qrow[ii] * s_f32[ii][nf * 16 + lr];
          acc[mi][nf][r] += sacc;
        }
      }
  }
  #pragma unroll
  for (int mi = 0; mi < 2; ++mi)
    #pragma unroll
    for (int r = 0; r < 4; ++r) {
      float d = den_l[mi][r];
      d += __shfl_xor(d, 1, 64); d += __shfl_xor(d, 2, 64);
      d += __shfl_xor(d, 4, 64); d += __shfl_xor(d, 8, 64);
      const int row_l = wrow + mi * 16 + lq * 4 + r;
      den_l[mi][r] = 1.0f / (d + dstate[row_l] + 1e-6f);
    }
  #pragma unroll
  for (int mi = 0; mi < 2; ++mi)
    #pragma unroll
    for (int r = 0; r < 4; ++r) {
      const size_t row_g = rowbase + wrow + mi * 16 + lq * 4 + r;
      const float inv = den_l[mi][r];
      #pragma unroll
      for (int nf = 0; nf < 8; ++nf)
        outp[row_g * DD + h * 128 + nf * 16 + lr] = (__bf16)(acc[mi][nf][r] * inv);
    }
}

// ---------------- LayerNorm (eps 1e-5), bf16 in -> bf16 out ----------------
__global__ __launch_bounds__(256) void ln_kernel(
    const bf16_t* __restrict__ hb, const float* __restrict__ g,
    const float* __restrict__ bta, bf16_t* __restrict__ out)
{
  const int row = blockIdx.x;
  const int t = threadIdx.x;
  const bf16x4 xb = *(const bf16x4*)(hb + (size_t)row * DD + t * 4);
  float4 x = make_float4((float)xb[0], (float)xb[1], (float)xb[2], (float)xb[3]);
  float s  = x.x + x.y + x.z + x.w;
  float s2 = x.x*x.x + x.y*x.y + x.z*x.z + x.w*x.w;
  #pragma unroll
  for (int off = 32; off > 0; off >>= 1) {
    s  += __shfl_down(s,  off, 64);
    s2 += __shfl_down(s2, off, 64);
  }
  __shared__ float ws[8];
  if ((t & 63) == 0) { ws[(t >> 6) * 2] = s; ws[(t >> 6) * 2 + 1] = s2; }
  __syncthreads();
  const float ts  = ws[0] + ws[2] + ws[4] + ws[6];
  const float ts2 = ws[1] + ws[3] + ws[5] + ws[7];
  const float mu  = ts * (1.0f / DD);
  const float var = ts2 * (1.0f / DD) - mu * mu;
  const float inv = rsqrtf(var + 1e-5f);
  const float4 gv = ((const float4*)g)[t];
  const float4 bv = ((const float4*)bta)[t];
  bf16x4 o;
  o[0] = (__bf16)((x.x - mu) * inv * gv.x + bv.x);
  o[1] = (__bf16)((x.y - mu) * inv * gv.y + bv.y);
  o[2] = (__bf16)((x.z - mu) * inv * gv.z + bv.z);
  o[3] = (__bf16)((x.w - mu) * inv * gv.w + bv.w);
  *(bf16x4*)(out + (size_t)row * DD + t * 4) = o;
}

extern "C" void kernel_launch(void* const* d_in, const int* in_sizes, int n_in,
                              void* d_out, int out_size, void* d_ws, size_t ws_size,
                              hipStream_t stream) {
  (void)in_sizes; (void)n_in; (void)out_size; (void)ws_size;
  const int*   x    = (const int*)d_in[0];
  const float* emb  = (const float*)d_in[1];
  const float* Wq   = (const float*)d_in[2];
  const float* Wk   = (const float*)d_in[3];
  const float* Wv   = (const float*)d_in[4];
  const float* Wo   = (const float*)d_in[5];
  const float* ln_g = (const float*)d_in[6];
  const float* ln_b = (const float*)d_in[7];
  const float* outW = (const float*)d_in[8];
  const float* outb = (const float*)d_in[9];
  float* out = (float*)d_out;

  char* ws = (char*)d_ws;
  bf16_t* ctx_bf  = (bf16_t*)(ws + 0);             // 16,777,216 (live till Wo residual)
  bf16_t* qbuf    = (bf16_t*)(ws + 16777216ull);   //  2,097,152
  bf16_t* kbuf    = (bf16_t*)(ws + 18874368ull);   //  2,097,152
  bf16_t* vTbuf   = (bf16_t*)(ws + 20971520ull);   // 16,777,216
  bf16_t* attn_bf = (bf16_t*)(ws + 37748736ull);   // 16,777,216 (attn out / Wo A; reused as h_bf)
  bf16_t* h_pre   = (bf16_t*)(ws + 54525952ull);   // 16,777,216 (Wo out, LN in)
  float*  Gbuf    = (float*) (ws + 71303168ull);   //  2,097,152
  float*  KSbuf   = (float*) (ws + 73400320ull);   //     16,384
  bf16_t* WqkvT   = (bf16_t*)(ws + 73416704ull);   //  2,621,440
  bf16_t* WoT     = (bf16_t*)(ws + 76038144ull);   //  2,097,152
  bf16_t* outWT   = (bf16_t*)(ws + 78135296ull);   // 65,536,000  (end 143,671,296)
  bf16_t* h_bf    = attn_bf;                       // LN out overlays attn_bf (dead after Wo)

  transpose_cvt<<<dim3(2, 8),   256, 0, stream>>>(Wq,   WqkvT,             DD, 128);
  transpose_cvt<<<dim3(2, 8),   256, 0, stream>>>(Wk,   WqkvT + 128 * DD,  DD, 128);
  transpose_cvt<<<dim3(16, 8),  256, 0, stream>>>(Wv,   WqkvT + 256 * DD,  DD, DD);
  transpose_cvt<<<dim3(16, 8),  256, 0, stream>>>(Wo,   WoT,               DD, DD);
  transpose_cvt<<<dim3(500, 8), 256, 0, stream>>>(outW, outWT,             DD, VV);

  ctx_kernel<<<BB * SS, 256, 0, stream>>>(x, emb, ctx_bf);

  // QKV projection (N=1280, grid 10*64=640)
  gemm128_kernel<3><<<(1280 / 128) * (BB * SS / 128), 256, 0, stream>>>(
      ctx_bf, WqkvT, nullptr, nullptr, nullptr, nullptr, qbuf, kbuf, vTbuf, 1280, DD);

  gstate_kernel<<<BB * NC * HH, 64, 0, stream>>>(kbuf, vTbuf, Gbuf, KSbuf);
  attn_kernel<<<BB * NC * HH, 512, 0, stream>>>(qbuf, kbuf, vTbuf, Gbuf, KSbuf, attn_bf);

  // out-proj + bf16 residual -> bf16 h_pre (N=1024, grid 8*64=512)
  gemm128_kernel<2><<<(DD / 128) * (BB * SS / 128), 256, 0, stream>>>(
      attn_bf, WoT, nullptr, h_pre, nullptr, ctx_bf, nullptr, nullptr, nullptr, DD, DD);

  ln_kernel<<<BB * SS, 256, 0, stream>>>(h_pre, ln_g, ln_b, h_bf);

  // logits + bias (N=32000, grid 250*64=16000)
  gemm128_kernel<1><<<(VV / 128) * (BB * SS / 128), 256, 0, stream>>>(
      h_bf, outWT, out, nullptr, outb, nullptr, nullptr, nullptr, nullptr, VV, DD);
}

// Round 16
// 779.197 us; speedup vs baseline: 1.7622x; 1.7622x over previous
//
#include <hip/hip_runtime.h>
#include <hip/hip_bf16.h>

typedef __bf16 bf16_t;
typedef __bf16 bf16x4 __attribute__((ext_vector_type(4)));
typedef __bf16 bf16x8 __attribute__((ext_vector_type(8)));
typedef float f32x4 __attribute__((ext_vector_type(4)));

#define BB 2
#define SS 4096
#define DD 1024
#define VV 32000
#define HH 8
#define CC 256
#define NC 16

#define GLD_LDS16(gp, lp) __builtin_amdgcn_global_load_lds( \
    (const __attribute__((address_space(1))) void*)(gp),    \
    (__attribute__((address_space(3))) void*)(lp), 16, 0, 0)

// ---------------- ctx: emb gather + 4-tap causal sum (bf16 only) ----------------
__global__ __launch_bounds__(256) void ctx_kernel(
    const int* __restrict__ x, const float* __restrict__ emb,
    bf16_t* __restrict__ ctxb)
{
  const int row = blockIdx.x;            // b*SS + s
  const int b = row >> 12, s = row & (SS - 1);
  const int t = threadIdx.x;             // d = t*4
  float4 a = make_float4(0.f, 0.f, 0.f, 0.f);
  #pragma unroll
  for (int o = 0; o < 4; ++o) {
    if (s - o >= 0) {
      const int idx = x[b * SS + s - o];
      const float4 e = *(const float4*)(emb + (size_t)idx * DD + t * 4);
      a.x += e.x; a.y += e.y; a.z += e.z; a.w += e.w;
    }
  }
  bf16x4 bv;
  bv[0] = (__bf16)a.x; bv[1] = (__bf16)a.y; bv[2] = (__bf16)a.z; bv[3] = (__bf16)a.w;
  *(bf16x4*)(ctxb + (size_t)row * DD + t * 4) = bv;
}

// ------- transpose + f32->bf16, 128x64 tile: dst[c][r]=src[r][c], 256B dst writes -------
__global__ __launch_bounds__(256) void transpose_cvt(
    const float* __restrict__ src, bf16_t* __restrict__ dst,
    int srcRows, int srcCols)
{
  __shared__ __align__(16) float tile[128][65];
  const int c0 = blockIdx.x * 64, r0 = blockIdx.y * 128;
  const int t = threadIdx.x;
  #pragma unroll
  for (int p = 0; p < 8; ++p) {
    const int r = p * 16 + (t >> 4);
    const int c = (t & 15) * 4;
    *(float4*)&tile[r][c] = *(const float4*)(src + (size_t)(r0 + r) * srcCols + c0 + c);
  }
  __syncthreads();
  #pragma unroll
  for (int p = 0; p < 4; ++p) {
    const int j = p * 16 + (t >> 4);     // dst row (src col)
    const int i0 = (t & 15) * 8;         // src row offset
    bf16x8 v;
    #pragma unroll
    for (int e = 0; e < 8; ++e) v[e] = (__bf16)tile[i0 + e][j];
    *(bf16x8*)(dst + (size_t)(c0 + j) * srcRows + r0 + i0) = v;
  }
}

// ========== m97-structure 128x128 GEMM, BK=64, 4 waves, 4 blocks/CU ==========
// R16: exact revert to the R14-confirmed kernel (791us total, logits 608us,
// 884 TF, MfmaUtil 41%, FETCH 0.29GB). Family ledger (all measured):
//  - schedule micro-edits (R3-R7): flat; implicit 4-block overlap (m114) is
//    this family's pipelining mechanism.
//  - explicit load overlap across MFMA/epilogue (R12/R13): FETCH 0.29->4.6GB
//    (destroys inter-block panel L2 reuse) -- refuted.
//  - __launch_bounds__(256,5) (R15): VGPR 64->48 squeeze, logits 1140us --
//    refuted; (256,4) is the optimum.
// EPI: 1 = +bias[col] -> f32 C (logits, nontemporal); 2 = +bf16 residual ->
// bf16 Cb (Wo); 3 = QKV epilogue (phi q/k -> qb/kb, v -> transposed vtb).
template<int EPI>
__global__ __launch_bounds__(256, 4) void gemm128_kernel(
    const bf16_t* __restrict__ A, const bf16_t* __restrict__ BT,
    float* __restrict__ C, bf16_t* __restrict__ Cb,
    const float* __restrict__ extraF, const bf16_t* __restrict__ extraB,
    bf16_t* __restrict__ qb, bf16_t* __restrict__ kbx, bf16_t* __restrict__ vtb,
    int N, int K)
{
  __shared__ __align__(16) bf16_t As[128 * 64];
  __shared__ __align__(16) bf16_t Bs[128 * 64];
  const int bid = blockIdx.x;
  const int i = bid >> 3, xcd = bid & 7;
  const int by = xcd * 8 + (i & 7);          // GY = M/128 = 64 always (M=8192)
  const int bx = i >> 3;
  const int n0 = bx * 128, m0 = by * 128;
  const int t = threadIdx.x;
  const int w = t >> 6, lane = t & 63;
  const int wm = (w >> 1) * 64, wn = (w & 1) * 64;
  const int lr = lane & 15, lq = lane >> 4;
  f32x4 acc[4][4] = {};

  for (int k0 = 0; k0 < K; k0 += 64) {
    #pragma unroll
    for (int j = 0; j < 4; ++j) {
      const int idx = j * 256 + t;
      const int r = idx >> 3;
      const int sc = ((idx & 7) ^ (r & 7)) * 8;      // pre-swizzled src col
      GLD_LDS16(A  + (size_t)(m0 + r) * K + k0 + sc, As + (size_t)idx * 8);
      GLD_LDS16(BT + (size_t)(n0 + r) * K + k0 + sc, Bs + (size_t)idx * 8);
    }
    asm volatile("s_waitcnt vmcnt(0)" ::: "memory");
    __syncthreads();
    bf16x8 af[4][2], bfr[4][2];
    #pragma unroll
    for (int ii = 0; ii < 4; ++ii) {
      const int ra = wm + ii * 16 + lr;
      const int rb = wn + ii * 16 + lr;
      #pragma unroll
      for (int ks = 0; ks < 2; ++ks) {
        const int col = ((ks * 4 + lq) ^ (lr & 7)) * 8;   // swizzled read col
        af[ii][ks]  = *(const bf16x8*)(As + ra * 64 + col);
        bfr[ii][ks] = *(const bf16x8*)(Bs + rb * 64 + col);
      }
    }
    #pragma unroll
    for (int mi = 0; mi < 4; ++mi)
      #pragma unroll
      for (int ni = 0; ni < 4; ++ni) {
        acc[mi][ni] = __builtin_amdgcn_mfma_f32_16x16x32_bf16(af[mi][0], bfr[ni][0], acc[mi][ni], 0, 0, 0);
        acc[mi][ni] = __builtin_amdgcn_mfma_f32_16x16x32_bf16(af[mi][1], bfr[ni][1], acc[mi][ni], 0, 0, 0);
      }
    __syncthreads();
  }

  // C/D layout: col=lane&15, row=(lane>>4)*4+reg  [m89-verified]
  if (EPI == 3) {
    #pragma unroll
    for (int mi = 0; mi < 4; ++mi) {
      const int row0 = m0 + wm + mi * 16 + lq * 4;
      #pragma unroll
      for (int ni = 0; ni < 4; ++ni) {
        const int col = n0 + wn + ni * 16 + lr;
        if (col < 256) {                       // q | k : phi -> bf16 (block-uniform)
          #pragma unroll
          for (int r = 0; r < 4; ++r) {
            float v = acc[mi][ni][r];
            v = v > 0.f ? v + 1.f : __expf(v);
            if (col < 128) qb [(size_t)(row0 + r) * 128 + col      ] = (__bf16)v;
            else           kbx[(size_t)(row0 + r) * 128 + col - 128] = (__bf16)v;
          }
        } else {                               // v -> transposed bf16
          const int vcol = col - 256;
          const int hh = vcol >> 7, dv = vcol & 127;
          const int bb = row0 >> 12, s0 = row0 & (SS - 1);
          bf16x4 pv;
          #pragma unroll
          for (int r = 0; r < 4; ++r) pv[r] = (__bf16)acc[mi][ni][r];
          *(bf16x4*)(vtb + ((size_t)((bb * HH + hh) * 128 + dv)) * SS + s0) = pv;
        }
      }
    }
    return;
  }
  #pragma unroll
  for (int mi = 0; mi < 4; ++mi) {
    #pragma unroll
    for (int r = 0; r < 4; ++r) {
      const int row = m0 + wm + mi * 16 + lq * 4 + r;
      #pragma unroll
      for (int ni = 0; ni < 4; ++ni) {
        const int col = n0 + wn + ni * 16 + lr;
        float v = acc[mi][ni][r];
        if (EPI == 1) {
          v += extraF[col];
          __builtin_nontemporal_store(v, &C[(size_t)row * N + col]);
        }
        if (EPI == 2) {
          v += (float)extraB[(size_t)row * N + col];
          Cb[(size_t)row * N + col] = (__bf16)v;
        }
      }
    }
  }
}

// ---------------- per-chunk G = K^T V (MFMA) and ksum ----------------
__global__ __launch_bounds__(64) void gstate_kernel(
    const bf16_t* __restrict__ kb, const bf16_t* __restrict__ vT,
    float* __restrict__ G, float* __restrict__ KS)
{
  const int bid = blockIdx.x;                  // b*128 + c*8 + h
  const int h = bid & 7, c = (bid >> 3) & 15, b = bid >> 7;
  const int lane = threadIdx.x;
  const int lr = lane & 15, lq = lane >> 4;
  __shared__ __align__(16) bf16_t ktl[16][264]; // k transposed: [i][s]
  for (int ss = 0; ss < 4; ++ss) {
    const int s = ss * 64 + lane;
    const bf16_t* src = kb + (size_t)(b * SS + c * CC + s) * 128 + h * 16;
    const bf16x8 v0 = *(const bf16x8*)src;
    const bf16x8 v1 = *(const bf16x8*)(src + 8);
    #pragma unroll
    for (int ii = 0; ii < 8; ++ii) { ktl[ii][s] = v0[ii]; ktl[8 + ii][s] = v1[ii]; }
  }
  __syncthreads();
  if (lane < 16) {
    float ks = 0.f;
    for (int s = 0; s < 256; ++s) ks += (float)ktl[lane][s];
    KS[((size_t)((b * NC + c) * HH + h)) * 16 + lane] = ks;
  }
  bf16x8 af[8];
  #pragma unroll
  for (int sk = 0; sk < 8; ++sk)
    af[sk] = *(const bf16x8*)&ktl[lr][sk * 32 + lq * 8];
  float* gout = G + ((size_t)((b * NC + c) * HH + h)) * 2048;
  #pragma unroll
  for (int nf = 0; nf < 8; ++nf) {
    f32x4 acc = {0.f, 0.f, 0.f, 0.f};
    #pragma unroll
    for (int sk = 0; sk < 8; ++sk) {
      const bf16x8 vb = *(const bf16x8*)(vT +
          ((size_t)((b * HH + h) * 128 + nf * 16 + lr)) * SS + c * CC + sk * 32 + lq * 8);
      acc = __builtin_amdgcn_mfma_f32_16x16x32_bf16(af[sk], vb, acc, 0, 0, 0);
    }
    #pragma unroll
    for (int r = 0; r < 4; ++r)
      gout[(size_t)(lq * 4 + r) * 128 + nf * 16 + lr] = acc[r];
  }
}

// ---------------- MFMA attention: intra(masked) + bypass + state ----------------
__global__ __launch_bounds__(512, 2) void attn_kernel(
    const bf16_t* __restrict__ qb, const bf16_t* __restrict__ kb,
    const bf16_t* __restrict__ vT, const float* __restrict__ Gb,
    const float* __restrict__ KS, bf16_t* __restrict__ outp)
{
  const int bid = blockIdx.x;                  // b*128 + c*8 + h
  const int h = bid & 7, c = (bid >> 3) & 15, b = bid >> 7;
  const int t = threadIdx.x;
  const int w = t >> 6, lane = t & 63;
  const int lr = lane & 15, lq = lane >> 4;
  const int rowbase = b * SS + c * CC;

  __shared__ __align__(16) bf16_t q_lds[256][24];
  __shared__ __align__(16) bf16_t k_lds[512][24];
  __shared__ __align__(16) bf16_t vt_lds[128][72];
  __shared__ __align__(16) bf16_t p_lds[8][32][72];
  __shared__ float s_f32[16][128];
  __shared__ float z_lds[16];
  __shared__ float dstate[256];

  if (t < 256) {                               // stage q rows (bf16, 32B each)
    const bf16_t* src = qb + (size_t)(rowbase + t) * 128 + h * 16;
    *(uint4*)&q_lds[t][0] = *(const uint4*)src;
    *(uint4*)&q_lds[t][8] = *(const uint4*)(src + 8);
  }
  {                                            // stage k rows: prev | cur
    if (t < 256 && c == 0) {
      const uint4 z = {0u, 0u, 0u, 0u};
      *(uint4*)&k_lds[t][0] = z; *(uint4*)&k_lds[t][8] = z;
    } else {
      const int sg = (t < 256) ? (c - 1) * CC + t : c * CC + (t - 256);
      const bf16_t* src = kb + (size_t)(b * SS + sg) * 128 + h * 16;
      *(uint4*)&k_lds[t][0] = *(const uint4*)src;
      *(uint4*)&k_lds[t][8] = *(const uint4*)(src + 8);
    }
  }
  if (t < 16) {                                // z[i] = sum_{j<=c-2} ksum_j[i]
    float z = 0.f;
    for (int j = 0; j + 2 <= c; ++j) z += KS[((size_t)((b * NC + j) * HH + h)) * 16 + t];
    z_lds[t] = z;
  }
  if (c >= 2) {                                // S = sum_{j<=c-2} G_j
    for (int idx = t; idx < 2048; idx += 512) {
      float sv = 0.f;
      for (int j = 0; j + 2 <= c; ++j)
        sv += Gb[((size_t)((b * NC + j) * HH + h)) * 2048 + idx];
      ((float*)s_f32)[idx] = sv;
    }
  }
  __syncthreads();
  if (t < 256) {                               // dstate[row] = q[row].z
    float d = 0.f;
    #pragma unroll
    for (int ii = 0; ii < 16; ++ii) d += (float)q_lds[t][ii] * z_lds[ii];
    dstate[t] = d;
  }

  const int wrow = w * 32;
  bf16x8 qf[2];
  #pragma unroll
  for (int mi = 0; mi < 2; ++mi) {
    bf16x8 v = {};
    if (lq < 2) v = *(const bf16x8*)&q_lds[wrow + mi * 16 + lr][lq * 8];
    qf[mi] = v;
  }
  f32x4 acc[2][8] = {};
  float den_l[2][4] = {};
  const int nc0 = (c == 0) ? 4 : 0;

  for (int nc = nc0; nc < 8; ++nc) {
    __syncthreads();                           // vt_lds reuse safe
    {                                          // stage V^T chunk [128 dv][64 keys]
      const int dv = t >> 2, kk = (t & 3) * 16;
      const int key0 = nc * 64;
      const int sg = (key0 < 256) ? (c - 1) * CC + key0 : c * CC + key0 - 256;
      const bf16_t* src = vT + ((size_t)((b * HH + h) * 128 + dv)) * SS + sg + kk;
      *(uint4*)&vt_lds[dv][kk]     = *(const uint4*)src;
      *(uint4*)&vt_lds[dv][kk + 8] = *(const uint4*)(src + 8);
    }
    __syncthreads();
    f32x4 attf[2][4];
    #pragma unroll
    for (int nf = 0; nf < 4; ++nf) {
      bf16x8 kv = {};
      if (lq < 2) kv = *(const bf16x8*)&k_lds[nc * 64 + nf * 16 + lr][lq * 8];
      #pragma unroll
      for (int mi = 0; mi < 2; ++mi) {
        const f32x4 zero = {0.f, 0.f, 0.f, 0.f};
        attf[mi][nf] = __builtin_amdgcn_mfma_f32_16x16x32_bf16(qf[mi], kv, zero, 0, 0, 0);
      }
    }
    #pragma unroll
    for (int mi = 0; mi < 2; ++mi)
      #pragma unroll
      for (int nf = 0; nf < 4; ++nf)
        #pragma unroll
        for (int r = 0; r < 4; ++r) {
          const int row_l = wrow + mi * 16 + lq * 4 + r;
          const int key_l = nc * 64 + nf * 16 + lr;
          float a = attf[mi][nf][r];
          if (key_l >= 256 && key_l - 256 > row_l) a = 0.f;
          den_l[mi][r] += a;
          p_lds[w][mi * 16 + lq * 4 + r][nf * 16 + lr] = (__bf16)a;
        }
    #pragma unroll
    for (int ks = 0; ks < 2; ++ks) {
      bf16x8 pa[2];
      #pragma unroll
      for (int mi = 0; mi < 2; ++mi)
        pa[mi] = *(const bf16x8*)&p_lds[w][mi * 16 + lr][ks * 32 + lq * 8];
      #pragma unroll
      for (int nf = 0; nf < 8; ++nf) {
        const bf16x8 vb = *(const bf16x8*)&vt_lds[nf * 16 + lr][ks * 32 + lq * 8];
        #pragma unroll
        for (int mi = 0; mi < 2; ++mi)
          acc[mi][nf] = __builtin_amdgcn_mfma_f32_16x16x32_bf16(pa[mi], vb, acc[mi][nf], 0, 0, 0);
      }
    }
  }

  if (c >= 2) {                                // state numerator: acc += q.S
    #pragma unroll
    for (int mi = 0; mi < 2; ++mi)
      for (int r = 0; r < 4; ++r) {
        const int row_l = wrow + mi * 16 + lq * 4 + r;
        float qrow[16];
        #pragma unroll
        for (int ii = 0; ii < 16; ++ii) qrow[ii] = (float)q_lds[row_l][ii];
        #pragma unroll
        for (int nf = 0; nf < 8; ++nf) {
          float sacc = 0.f;
          #pragma unroll
          for (int ii = 0; ii < 16; ++ii) sacc += qrow[ii] * s_f32[ii][nf * 16 + lr];
          acc[mi][nf][r] += sacc;
        }
      }
  }
  #pragma unroll
  for (int mi = 0; mi < 2; ++mi)
    #pragma unroll
    for (int r = 0; r < 4; ++r) {
      float d = den_l[mi][r];
      d += __shfl_xor(d, 1, 64); d += __shfl_xor(d, 2, 64);
      d += __shfl_xor(d, 4, 64); d += __shfl_xor(d, 8, 64);
      const int row_l = wrow + mi * 16 + lq * 4 + r;
      den_l[mi][r] = 1.0f / (d + dstate[row_l] + 1e-6f);
    }
  #pragma unroll
  for (int mi = 0; mi < 2; ++mi)
    #pragma unroll
    for (int r = 0; r < 4; ++r) {
      const size_t row_g = rowbase + wrow + mi * 16 + lq * 4 + r;
      const float inv = den_l[mi][r];
      #pragma unroll
      for (int nf = 0; nf < 8; ++nf)
        outp[row_g * DD + h * 128 + nf * 16 + lr] = (__bf16)(acc[mi][nf][r] * inv);
    }
}

// ---------------- LayerNorm (eps 1e-5), bf16 in -> bf16 out ----------------
__global__ __launch_bounds__(256) void ln_kernel(
    const bf16_t* __restrict__ hb, const float* __restrict__ g,
    const float* __restrict__ bta, bf16_t* __restrict__ out)
{
  const int row = blockIdx.x;
  const int t = threadIdx.x;
  const bf16x4 xb = *(const bf16x4*)(hb + (size_t)row * DD + t * 4);
  float4 x = make_float4((float)xb[0], (float)xb[1], (float)xb[2], (float)xb[3]);
  float s  = x.x + x.y + x.z + x.w;
  float s2 = x.x*x.x + x.y*x.y + x.z*x.z + x.w*x.w;
  #pragma unroll
  for (int off = 32; off > 0; off >>= 1) {
    s  += __shfl_down(s,  off, 64);
    s2 += __shfl_down(s2, off, 64);
  }
  __shared__ float ws[8];
  if ((t & 63) == 0) { ws[(t >> 6) * 2] = s; ws[(t >> 6) * 2 + 1] = s2; }
  __syncthreads();
  const float ts  = ws[0] + ws[2] + ws[4] + ws[6];
  const float ts2 = ws[1] + ws[3] + ws[5] + ws[7];
  const float mu  = ts * (1.0f / DD);
  const float var = ts2 * (1.0f / DD) - mu * mu;
  const float inv = rsqrtf(var + 1e-5f);
  const float4 gv = ((const float4*)g)[t];
  const float4 bv = ((const float4*)bta)[t];
  bf16x4 o;
  o[0] = (__bf16)((x.x - mu) * inv * gv.x + bv.x);
  o[1] = (__bf16)((x.y - mu) * inv * gv.y + bv.y);
  o[2] = (__bf16)((x.z - mu) * inv * gv.z + bv.z);
  o[3] = (__bf16)((x.w - mu) * inv * gv.w + bv.w);
  *(bf16x4*)(out + (size_t)row * DD + t * 4) = o;
}

extern "C" void kernel_launch(void* const* d_in, const int* in_sizes, int n_in,
                              void* d_out, int out_size, void* d_ws, size_t ws_size,
                              hipStream_t stream) {
  (void)in_sizes; (void)n_in; (void)out_size; (void)ws_size;
  const int*   x    = (const int*)d_in[0];
  const float* emb  = (const float*)d_in[1];
  const float* Wq   = (const float*)d_in[2];
  const float* Wk   = (const float*)d_in[3];
  const float* Wv   = (const float*)d_in[4];
  const float* Wo   = (const float*)d_in[5];
  const float* ln_g = (const float*)d_in[6];
  const float* ln_b = (const float*)d_in[7];
  const float* outW = (const float*)d_in[8];
  const float* outb = (const float*)d_in[9];
  float* out = (float*)d_out;

  char* ws = (char*)d_ws;
  bf16_t* ctx_bf  = (bf16_t*)(ws + 0);             // 16,777,216 (live till Wo residual)
  bf16_t* qbuf    = (bf16_t*)(ws + 16777216ull);   //  2,097,152
  bf16_t* kbuf    = (bf16_t*)(ws + 18874368ull);   //  2,097,152
  bf16_t* vTbuf   = (bf16_t*)(ws + 20971520ull);   // 16,777,216
  bf16_t* attn_bf = (bf16_t*)(ws + 37748736ull);   // 16,777,216 (attn out / Wo A; reused as h_bf)
  bf16_t* h_pre   = (bf16_t*)(ws + 54525952ull);   // 16,777,216 (Wo out, LN in)
  float*  Gbuf    = (float*) (ws + 71303168ull);   //  2,097,152
  float*  KSbuf   = (float*) (ws + 73400320ull);   //     16,384
  bf16_t* WqkvT   = (bf16_t*)(ws + 73416704ull);   //  2,621,440
  bf16_t* WoT     = (bf16_t*)(ws + 76038144ull);   //  2,097,152
  bf16_t* outWT   = (bf16_t*)(ws + 78135296ull);   // 65,536,000  (end 143,671,296)
  bf16_t* h_bf    = attn_bf;                       // LN out overlays attn_bf (dead after Wo)

  transpose_cvt<<<dim3(2, 8),   256, 0, stream>>>(Wq,   WqkvT,             DD, 128);
  transpose_cvt<<<dim3(2, 8),   256, 0, stream>>>(Wk,   WqkvT + 128 * DD,  DD, 128);
  transpose_cvt<<<dim3(16, 8),  256, 0, stream>>>(Wv,   WqkvT + 256 * DD,  DD, DD);
  transpose_cvt<<<dim3(16, 8),  256, 0, stream>>>(Wo,   WoT,               DD, DD);
  transpose_cvt<<<dim3(500, 8), 256, 0, stream>>>(outW, outWT,             DD, VV);

  ctx_kernel<<<BB * SS, 256, 0, stream>>>(x, emb, ctx_bf);

  // QKV projection (N=1280, grid 10*64=640)
  gemm128_kernel<3><<<(1280 / 128) * (BB * SS / 128), 256, 0, stream>>>(
      ctx_bf, WqkvT, nullptr, nullptr, nullptr, nullptr, qbuf, kbuf, vTbuf, 1280, DD);

  gstate_kernel<<<BB * NC * HH, 64, 0, stream>>>(kbuf, vTbuf, Gbuf, KSbuf);
  attn_kernel<<<BB * NC * HH, 512, 0, stream>>>(qbuf, kbuf, vTbuf, Gbuf, KSbuf, attn_bf);

  // out-proj + bf16 residual -> bf16 h_pre (N=1024, grid 8*64=512)
  gemm128_kernel<2><<<(DD / 128) * (BB * SS / 128), 256, 0, stream>>>(
      attn_bf, WoT, nullptr, h_pre, nullptr, ctx_bf, nullptr, nullptr, nullptr, DD, DD);

  ln_kernel<<<BB * SS, 256, 0, stream>>>(h_pre, ln_g, ln_b, h_bf);

  // logits + bias (N=32000, grid 250*64=16000)
  gemm128_kernel<1><<<(VV / 128) * (BB * SS / 128), 256, 0, stream>>>(
      h_bf, outWT, out, nullptr, outb, nullptr, nullptr, nullptr, nullptr, VV, DD);
}